// Round 1
// baseline (271.892 us; speedup 1.0000x reference)
//
#include <hip/hip_runtime.h>

#define BB 8
#define CC 64
#define HH 112
#define WW 112
#define HWs (HH * WW)                     // 12544
#define KEYN 9
#define NOFF 10                           // only offset channels 0..9 are used
#define PIX_PER_BLK 64
#define BLKS_PER_B (HWs / PIX_PER_BLK)    // 196
#define NBLK (BB * BLKS_PER_B)            // 1568

// Kernel 1: conv1x1s. lane = pixel (64 pixels per block), wave w computes a
// subset of output channels with wave-uniform float4 weight broadcasts.
// key_feature is written PIXEL-MAJOR [b*HW + s][64] via LDS transpose so the
// sampling kernel's gathers are fully coalesced.
__global__ __launch_bounds__(256) void precompute_kernel(
    const float* __restrict__ query, const float* __restrict__ key,
    const float* __restrict__ w_refer, const float* __restrict__ b_refer,
    const float* __restrict__ w_attn, const float* __restrict__ b_attn,
    const float* __restrict__ w_off, const float* __restrict__ b_off,
    float* __restrict__ Kf, float* __restrict__ A, float* __restrict__ O)
{
    __shared__ float OutT[64 * 65];   // [pixel][65] padded: conflict-free transpose
    __shared__ float L[64 * 19];      // per-pixel 9 attn logits + 10 offsets
    __shared__ float Mx[64];
    __shared__ float Sinv[64];

    const int t = threadIdx.x;
    const int l = t & 63;             // pixel within block
    const int w = t >> 6;             // wave index
    const int blk = blockIdx.x;
    const int b = blk / BLKS_PER_B;
    const int s0 = (blk - b * BLKS_PER_B) * PIX_PER_BLK;
    const size_t inbase = (size_t)b * CC * HWs + (size_t)(s0 + l);

    float reg[CC];

    // ---- key conv: load all 64 input channels for this lane's pixel (coalesced
    // across lanes per channel plane), then 16 output channels per wave.
    #pragma unroll
    for (int c = 0; c < CC; ++c) reg[c] = key[inbase + (size_t)c * HWs];

    for (int oi = 0; oi < 16; ++oi) {
        const int o = w * 16 + oi;
        const float4* wr = reinterpret_cast<const float4*>(w_refer + o * CC);
        float acc = b_refer[o];
        #pragma unroll
        for (int c4 = 0; c4 < 16; ++c4) {
            const float4 wv = wr[c4];
            acc = fmaf(reg[4 * c4 + 0], wv.x, acc);
            acc = fmaf(reg[4 * c4 + 1], wv.y, acc);
            acc = fmaf(reg[4 * c4 + 2], wv.z, acc);
            acc = fmaf(reg[4 * c4 + 3], wv.w, acc);
        }
        OutT[l * 65 + o] = acc;       // bank (l+o)%32 -> 2-way (free)
    }

    // ---- query convs: 19 outputs (9 attn logits, 10 offsets), round-robin by wave
    #pragma unroll
    for (int c = 0; c < CC; ++c) reg[c] = query[inbase + (size_t)c * HWs];

    for (int o = w; o < (KEYN + NOFF); o += 4) {
        const float* wrow = (o < KEYN) ? (w_attn + o * CC) : (w_off + (o - KEYN) * CC);
        float acc = (o < KEYN) ? b_attn[o] : b_off[o - KEYN];
        const float4* wr = reinterpret_cast<const float4*>(wrow);
        #pragma unroll
        for (int c4 = 0; c4 < 16; ++c4) {
            const float4 wv = wr[c4];
            acc = fmaf(reg[4 * c4 + 0], wv.x, acc);
            acc = fmaf(reg[4 * c4 + 1], wv.y, acc);
            acc = fmaf(reg[4 * c4 + 2], wv.z, acc);
            acc = fmaf(reg[4 * c4 + 3], wv.w, acc);
        }
        L[l * 19 + o] = acc;
    }
    __syncthreads();

    // ---- coalesced pixel-major key_feature store
    {
        const size_t obase = ((size_t)b * HWs + s0) * CC;
        #pragma unroll
        for (int i = 0; i < 16; ++i) {
            const int p = i * 4 + w;
            Kf[obase + (size_t)p * CC + l] = OutT[p * 65 + l];
        }
    }

    // ---- softmax reduction per pixel
    if (t < 64) {
        const int p = t;
        float m = L[p * 19 + 0];
        #pragma unroll
        for (int k = 1; k < KEYN; ++k) m = fmaxf(m, L[p * 19 + k]);
        float s = 0.f;
        #pragma unroll
        for (int k = 0; k < KEYN; ++k) s += expf(L[p * 19 + k] - m);
        Mx[p] = m;
        Sinv[p] = 1.0f / s;
    }
    __syncthreads();

    // ---- contiguous (pixel-major) attn / offset stores, coalesced over flat idx
    {
        const size_t abase = ((size_t)b * HWs + s0) * KEYN;
        for (int f = t; f < PIX_PER_BLK * KEYN; f += 256) {
            const int p = f / KEYN;
            const int k = f - p * KEYN;
            A[abase + f] = expf(L[p * 19 + k] - Mx[p]) * Sinv[p];
        }
        const size_t obase = ((size_t)b * HWs + s0) * NOFF;
        for (int f = t; f < PIX_PER_BLK * NOFF; f += 256) {
            const int p = f / NOFF;
            const int j = f - p * NOFF;
            O[obase + f] = L[p * 19 + KEYN + j];
        }
    }
}

// Kernel 2: deformable sampling + attn-weighted sum. lane = channel, each wave
// walks 16 pixels; every corner gather is one coalesced 256B load from
// pixel-major Kf. Output transposed back to [b,c,h,w] through LDS.
__global__ __launch_bounds__(256) void sample_kernel(
    const float* __restrict__ Kf, const float* __restrict__ A,
    const float* __restrict__ O, float* __restrict__ out)
{
    __shared__ float OutT[64 * 65];
    const int t = threadIdx.x;
    const int l = t & 63;             // channel
    const int w = t >> 6;
    const int blk = blockIdx.x;
    const int b = blk / BLKS_PER_B;
    const int s0 = (blk - b * BLKS_PER_B) * PIX_PER_BLK;
    const size_t kfbase = (size_t)b * HWs * CC;

    for (int i = 0; i < 16; ++i) {
        const int p = w * 16 + i;
        const int s = s0 + p;
        const int y = s / WW;
        const int x = s - y * WW;
        const size_t pix = (size_t)b * HWs + s;

        float a[KEYN], off[NOFF];
        #pragma unroll
        for (int k = 0; k < KEYN; ++k) a[k] = A[pix * KEYN + k];    // uniform -> broadcast
        #pragma unroll
        for (int j = 0; j < NOFF; ++j) off[j] = O[pix * NOFF + j];

        float acc = 0.f;
        #pragma unroll
        for (int k = 0; k < KEYN; ++k) {
            const float py = off[k] + (float)y;       // dy = offset[k]
            const float px = off[k + 1] + (float)x;   // dx = offset[k+1] (overlapping slices)
            const float fy = floorf(py);
            const float fx = floorf(px);
            const float wy1 = py - fy, wx1 = px - fx;
            const float wy0 = 1.f - wy1, wx0 = 1.f - wx1;
            const int iy0 = (int)fy, ix0 = (int)fx;
            const int iy1 = iy0 + 1, ix1 = ix0 + 1;
            const int yc0 = min(max(iy0, 0), HH - 1);
            const int yc1 = min(max(iy1, 0), HH - 1);
            const int xc0 = min(max(ix0, 0), WW - 1);
            const int xc1 = min(max(ix1, 0), WW - 1);
            const float my0 = (iy0 >= 0 && iy0 < HH) ? 1.f : 0.f;
            const float my1 = (iy1 >= 0 && iy1 < HH) ? 1.f : 0.f;
            const float mx0 = (ix0 >= 0 && ix0 < WW) ? 1.f : 0.f;
            const float mx1 = (ix1 >= 0 && ix1 < WW) ? 1.f : 0.f;
            const float v00 = Kf[kfbase + (size_t)(yc0 * WW + xc0) * CC + l] * (my0 * mx0);
            const float v01 = Kf[kfbase + (size_t)(yc0 * WW + xc1) * CC + l] * (my0 * mx1);
            const float v10 = Kf[kfbase + (size_t)(yc1 * WW + xc0) * CC + l] * (my1 * mx0);
            const float v11 = Kf[kfbase + (size_t)(yc1 * WW + xc1) * CC + l] * (my1 * mx1);
            const float bil = wy0 * fmaf(wx0, v00, wx1 * v01)
                            + wy1 * fmaf(wx0, v10, wx1 * v11);
            acc = fmaf(a[k], bil, acc);
        }
        OutT[p * 65 + l] = acc;
    }
    __syncthreads();

    const size_t obase = (size_t)b * CC * HWs + s0;
    #pragma unroll
    for (int i = 0; i < 16; ++i) {
        const int c = i * 4 + w;
        out[obase + (size_t)c * HWs + l] = OutT[l * 65 + c];  // coalesced, conflict-free
    }
}

extern "C" void kernel_launch(void* const* d_in, const int* in_sizes, int n_in,
                              void* d_out, int out_size, void* d_ws, size_t ws_size,
                              hipStream_t stream)
{
    const float* query   = (const float*)d_in[0];
    const float* key     = (const float*)d_in[1];
    const float* w_refer = (const float*)d_in[2];
    const float* b_refer = (const float*)d_in[3];
    const float* w_attn  = (const float*)d_in[4];
    const float* b_attn  = (const float*)d_in[5];
    const float* w_off   = (const float*)d_in[6];
    const float* b_off   = (const float*)d_in[7];
    float* out = (float*)d_out;

    float* Kf = (float*)d_ws;                              // [B*HW][64]  25.7 MB
    float* A  = Kf + (size_t)BB * HWs * CC;                // [B*HW][9]    3.6 MB
    float* O  = A + (size_t)BB * HWs * KEYN;               // [B*HW][10]   4.0 MB

    hipLaunchKernelGGL(precompute_kernel, dim3(NBLK), dim3(256), 0, stream,
                       query, key, w_refer, b_refer, w_attn, b_attn, w_off, b_off,
                       Kf, A, O);
    hipLaunchKernelGGL(sample_kernel, dim3(NBLK), dim3(256), 0, stream,
                       Kf, A, O, out);
}